// Round 1
// baseline (324.284 us; speedup 1.0000x reference)
//
#include <hip/hip_runtime.h>
#include <math.h>

#define KK 48
#define TT 1024
#define BB 512
#define START_TAG 46
#define END_TAG 47

// ---------------------------------------------------------------------------
// Kernel A: gold (numerator) score per sentence.
// gold[b] = sum_t trans[tag_t, tag_{t-1}] + feat[t, tag_t]  (+ trans[END, tag_{T-1}])
// Pure gather + block reduction. Writes to d_ws.
// ---------------------------------------------------------------------------
__global__ __launch_bounds__(256) void gold_kernel(const float* __restrict__ feats,
                                                   const float* __restrict__ trans,
                                                   const int* __restrict__ tags,
                                                   float* __restrict__ gold) {
    const int b = blockIdx.x;
    const int tid = threadIdx.x;
    const int* tg = tags + b * TT;
    const float* fb = feats + (size_t)b * TT * KK;

    float acc = 0.0f;
    for (int t = tid; t < TT; t += 256) {
        int cur = tg[t];
        int prev = (t == 0) ? START_TAG : tg[t - 1];
        acc += trans[cur * KK + prev] + fb[t * KK + cur];
    }
    // wave (64-lane) butterfly reduce
    #pragma unroll
    for (int off = 32; off; off >>= 1) acc += __shfl_xor(acc, off, 64);

    __shared__ float wsum[4];
    const int wave = tid >> 6;
    if ((tid & 63) == 0) wsum[wave] = acc;
    __syncthreads();
    if (tid == 0) {
        float tot = wsum[0] + wsum[1] + wsum[2] + wsum[3];
        tot += trans[END_TAG * KK + tg[TT - 1]];
        gold[b] = tot;
    }
}

// ---------------------------------------------------------------------------
// Kernel B: forward algorithm (partition function), one wave per sentence.
// Linear-domain recurrence: ea_new[i] = (sum_j E[i,j]*ea[j]) * exp(feat[t,i]),
// with uniform power-of-2 rescale every 4 steps (exponent tracked in int esum).
// lane = tag (lanes 48..63 compute garbage, masked everywhere it matters).
// Single wave per block => no __syncthreads in the T-loop.
// ---------------------------------------------------------------------------
__global__ __launch_bounds__(64) void fwd_kernel(const float* __restrict__ feats,
                                                 const float* __restrict__ trans,
                                                 const float* __restrict__ gold,
                                                 float* __restrict__ out) {
    const int b = blockIdx.x;
    const int i = threadIdx.x;
    const int ci = (i < KK) ? i : 0;   // clamped lane->tag (avoids OOB feat loads)
    const float* fb = feats + (size_t)b * TT * KK;

    // E row i in registers: E[j] = exp(trans[i][j]).  exp(-1e5) == 0 handles the
    // START-row / END-col structural masking automatically.
    float E[KK];
    #pragma unroll
    for (int j = 0; j < KK; ++j) E[j] = __expf(trans[ci * KK + j]);
    const float eEND = __expf(trans[END_TAG * KK + ci]);   // col END -> 0 automatically

    __shared__ __attribute__((aligned(16))) float ea_sh[KK];
    if (i < KK) ea_sh[i] = (i == START_TAG) ? 1.0f : 0.0f;
    __syncthreads();   // once, outside the loop

    const float4* ea4p = (const float4*)ea_sh;

    int esum = 0;          // exact power-of-2 scaling ledger (uniform across lanes)
    float sLast = 0.0f;

    // feats prefetch: group of 4 steps, load next group while processing current
    float fr[4];
    #pragma unroll
    for (int k = 0; k < 4; ++k) fr[k] = fb[k * KK + ci];

    for (int g = 0; g < TT / 4; ++g) {
        float fn[4] = {0.f, 0.f, 0.f, 0.f};
        if (g < TT / 4 - 1) {
            #pragma unroll
            for (int k = 0; k < 4; ++k) fn[k] = fb[((g + 1) * 4 + k) * KK + ci];
        }
        // exp(feat) for the current group — raw values loaded a full group ago,
        // so this is latency-free and off the per-step critical path
        float ef[4];
        #pragma unroll
        for (int k = 0; k < 4; ++k) ef[k] = __expf(fr[k]);

        #pragma unroll
        for (int k = 0; k < 4; ++k) {
            // broadcast read of previous alpha (linear domain) from LDS
            float4 ev[12];
            #pragma unroll
            for (int c = 0; c < 12; ++c) ev[c] = ea4p[c];

            float a0 = 0.f, a1 = 0.f, a2 = 0.f, a3 = 0.f;
            #pragma unroll
            for (int c = 0; c < 12; ++c) {
                a0 = fmaf(E[4 * c + 0], ev[c].x, a0);
                a1 = fmaf(E[4 * c + 1], ev[c].y, a1);
                a2 = fmaf(E[4 * c + 2], ev[c].z, a2);
                a3 = fmaf(E[4 * c + 3], ev[c].w, a3);
            }
            float s = (a0 + a1) + (a2 + a3);
            s *= ef[k];

            // uniform power-of-2 rescale once per group (at k==1: ea_sh[0] is
            // strictly positive from step 1 onward). ev[0].x is wave-uniform.
            if (k == 1) {
                int e0 = ((__float_as_int(ev[0].x) >> 23) & 0xff) - 127;
                esum += e0;
                s *= __int_as_float((127 - e0) << 23);   // * 2^-e0, exact
            }

            sLast = s;
            if (i < KK) ea_sh[i] = s;   // same-wave DS ops are ordered; no barrier
        }
        #pragma unroll
        for (int k = 0; k < 4; ++k) fr[k] = fn[k];
    }

    // log_z = log(sum_i ea[i] * exp(trans[END][i])) + esum*ln2
    float val = (i < KK) ? sLast * eEND : 0.0f;
    #pragma unroll
    for (int off = 32; off; off >>= 1) val += __shfl_xor(val, off, 64);

    if (i == 0) {
        float logz = __logf(val) + (float)esum * 0.6931471805599453f;
        out[b] = logz - gold[b];
    }
}

extern "C" void kernel_launch(void* const* d_in, const int* in_sizes, int n_in,
                              void* d_out, int out_size, void* d_ws, size_t ws_size,
                              hipStream_t stream) {
    const float* feats = (const float*)d_in[0];
    const float* trans = (const float*)d_in[1];
    const int* tags = (const int*)d_in[2];
    float* out = (float*)d_out;
    float* gold = (float*)d_ws;   // 512 floats of scratch

    gold_kernel<<<BB, 256, 0, stream>>>(feats, trans, tags, gold);
    fwd_kernel<<<BB, 64, 0, stream>>>(feats, trans, gold, out);
}